// Round 5
// baseline (408.894 us; speedup 1.0000x reference)
//
#include <hip/hip_runtime.h>
#include <stdint.h>

// Problem constants (fixed by setup_inputs):
//   x: (16, 3, 1024, 1024) f32; control_points: (1, 2, 35, 35) f32
//   out = concat(transformed (16,3,1024,1024), deformation_field (2,1024,1024))
#define HW      1024
#define PLANE   (HW * HW)
#define NPLANES 48          // 16 * 3
#define CP      35
#define CPN     (CP * CP)
#define PPT     8           // planes per thread
#define ZCHUNKS (NPLANES / PPT)   // 6

typedef float f2v __attribute__((ext_vector_type(2)));

__global__ __launch_bounds__(256) void bspline_fused_kernel(
    const float* __restrict__ x,
    const float* __restrict__ cp,   // (2, 35, 35)
    float* __restrict__ out)
{
    // ---- XCD-aware remap (T1). Dispatch-linear bid -> round-robin XCD = bid&7.
    // Give each XCD a contiguous 128-row band per z-chunk so the two readers
    // of every input row (output rows i, i+1) share an L2. Bijective:
    // 24576 blocks = 8 XCD x (6 z x 128 rows x 4 colchunks).
    const int bid = (blockIdx.z * gridDim.y + blockIdx.y) * gridDim.x + blockIdx.x;
    const int xcd = bid & 7;
    const int idx = bid >> 3;           // 0..3071 within XCD
    const int zc  = idx >> 9;           // 0..5   (z-chunk)
    const int r   = idx & 511;
    const int i   = (xcd << 7) + (r >> 2);          // row 0..1023
    const int j   = (r & 3) * 256 + threadIdx.x;    // col
    const int pix = i * HW + j;

    // normalized grid coords (linspace(-1,1,1024))
    const float gx = (float)j * (2.0f / 1023.0f) - 1.0f;
    const float gy = (float)i * (2.0f / 1023.0f) - 1.0f;

    // ---- deformation field: bilinear sample of control points ----
    const float cpxc = gx * 17.0f + 17.0f;     // (cpx-1)/2 = 17
    const float cpyc = gy * 17.0f + 17.0f;
    float ix = (cpxc + 1.0f) * 0.5f * 34.0f;   // (W-1) = 34
    float iy = (cpyc + 1.0f) * 0.5f * 34.0f;
    ix = fminf(fmaxf(ix, 0.0f), 34.0f);
    iy = fminf(fmaxf(iy, 0.0f), 34.0f);
    const float ix0f = floorf(ix), iy0f = floorf(iy);
    const float wx = ix - ix0f,    wy = iy - iy0f;
    const int ix0 = (int)ix0f, iy0 = (int)iy0f;
    const int ix1 = min(ix0 + 1, 34), iy1 = min(iy0 + 1, 34);

    const int o00c = iy0 * CP + ix0, o01c = iy0 * CP + ix1;
    const int o10c = iy1 * CP + ix0, o11c = iy1 * CP + ix1;

    float df[2];
    #pragma unroll
    for (int c = 0; c < 2; ++c) {
        const float* cpc = cp + c * CPN;
        const float v00 = cpc[o00c], v01 = cpc[o01c];
        const float v10 = cpc[o10c], v11 = cpc[o11c];
        const float top = v00 * (1.0f - wx) + v01 * wx;
        const float bot = v10 * (1.0f - wx) + v11 * wx;
        df[c] = top * (1.0f - wy) + bot * wy;
    }

    // deformation_field output lives after the 48 transformed planes;
    // only the zc==0 slice writes it (each (i,j) appears exactly once with zc==0)
    if (zc == 0) {
        out[NPLANES * PLANE + 0 * PLANE + pix] = df[0];
        out[NPLANES * PLANE + 1 * PLANE + pix] = df[1];
    }

    // ---- image sampling coords (note df channel swap per reference) ----
    const float sxn = gx + df[1];
    const float syn = gy + df[0];
    float fx = (sxn + 1.0f) * 0.5f * 1023.0f;
    float fy = (syn + 1.0f) * 0.5f * 1023.0f;
    fx = fminf(fmaxf(fx, 0.0f), 1023.0f);
    fy = fminf(fmaxf(fy, 0.0f), 1023.0f);
    const float fx0f = floorf(fx), fy0f = floorf(fy);
    const float ux = fx - fx0f,    uy = fy - fy0f;
    const int X0 = (int)fx0f, Y0 = (int)fy0f;
    const int Y1 = min(Y0 + 1, 1023);

    // x-neighbor pair (b[o00], b[o00+1]) as ONE dwordx2 (4B-aligned; HW
    // handles the 8B-unaligned case). Border fold: X0==1023 only when
    // fx==1023.0 exactly (ux==0): shift pair base down 1, weights (0,1).
    const int bshift = (X0 >= 1023) ? 1 : 0;
    const uint32_t vot = (uint32_t)(Y0 * HW + X0 - bshift) * 4u;  // byte off, row Y0
    const uint32_t vob = (uint32_t)(Y1 * HW + X0 - bshift) * 4u;  // byte off, row Y1
    const float wbx = bshift ? 1.0f : (fx - fx0f);
    const float wax = 1.0f - wbx;
    const float omuy = 1.0f - uy;

    // ---- 8 planes per thread; all 16 loads forced in flight (round-4 asm) ----
    const int p0 = zc * PPT;
    const float* __restrict__ xp = x + (size_t)p0 * PLANE;
    float* __restrict__ op = out + (size_t)p0 * PLANE + pix;

    const float* b0 = xp + 0 * (size_t)PLANE;
    const float* b1 = xp + 1 * (size_t)PLANE;
    const float* b2 = xp + 2 * (size_t)PLANE;
    const float* b3 = xp + 3 * (size_t)PLANE;
    const float* b4 = xp + 4 * (size_t)PLANE;
    const float* b5 = xp + 5 * (size_t)PLANE;
    const float* b6 = xp + 6 * (size_t)PLANE;
    const float* b7 = xp + 7 * (size_t)PLANE;

    f2v t0, t1, t2, t3, t4, t5, t6, t7;   // row Y0 pairs
    f2v m0, m1, m2, m3, m4, m5, m6, m7;   // row Y1 pairs
    asm volatile(
        "global_load_dwordx2 %[t0], %[ot], %[p0]\n\t"
        "global_load_dwordx2 %[m0], %[ob], %[p0]\n\t"
        "global_load_dwordx2 %[t1], %[ot], %[p1]\n\t"
        "global_load_dwordx2 %[m1], %[ob], %[p1]\n\t"
        "global_load_dwordx2 %[t2], %[ot], %[p2]\n\t"
        "global_load_dwordx2 %[m2], %[ob], %[p2]\n\t"
        "global_load_dwordx2 %[t3], %[ot], %[p3]\n\t"
        "global_load_dwordx2 %[m3], %[ob], %[p3]\n\t"
        "global_load_dwordx2 %[t4], %[ot], %[p4]\n\t"
        "global_load_dwordx2 %[m4], %[ob], %[p4]\n\t"
        "global_load_dwordx2 %[t5], %[ot], %[p5]\n\t"
        "global_load_dwordx2 %[m5], %[ob], %[p5]\n\t"
        "global_load_dwordx2 %[t6], %[ot], %[p6]\n\t"
        "global_load_dwordx2 %[m6], %[ob], %[p6]\n\t"
        "global_load_dwordx2 %[t7], %[ot], %[p7]\n\t"
        "global_load_dwordx2 %[m7], %[ob], %[p7]\n\t"
        "s_waitcnt vmcnt(0)"
        : [t0]"=&v"(t0), [m0]"=&v"(m0), [t1]"=&v"(t1), [m1]"=&v"(m1),
          [t2]"=&v"(t2), [m2]"=&v"(m2), [t3]"=&v"(t3), [m3]"=&v"(m3),
          [t4]"=&v"(t4), [m4]"=&v"(m4), [t5]"=&v"(t5), [m5]"=&v"(m5),
          [t6]"=&v"(t6), [m6]"=&v"(m6), [t7]"=&v"(t7), [m7]"=&v"(m7)
        : [ot]"v"(vot), [ob]"v"(vob),
          [p0]"s"(b0), [p1]"s"(b1), [p2]"s"(b2), [p3]"s"(b3),
          [p4]"s"(b4), [p5]"s"(b5), [p6]"s"(b6), [p7]"s"(b7)
        : "memory");

    f2v t[PPT] = {t0, t1, t2, t3, t4, t5, t6, t7};
    f2v m[PPT] = {m0, m1, m2, m3, m4, m5, m6, m7};
    #pragma unroll
    for (int p = 0; p < PPT; ++p) {
        const float top = t[p].x * wax + t[p].y * wbx;
        const float bot = m[p].x * wax + m[p].y * wbx;
        const float r   = top * omuy + bot * uy;
        __builtin_nontemporal_store(r, op + (size_t)p * PLANE);
    }
}

extern "C" void kernel_launch(void* const* d_in, const int* in_sizes, int n_in,
                              void* d_out, int out_size, void* d_ws, size_t ws_size,
                              hipStream_t stream) {
    const float* x  = (const float*)d_in[0];
    const float* cp = (const float*)d_in[1];
    float* out = (float*)d_out;

    dim3 block(256, 1, 1);
    dim3 grid(HW / 256, HW, ZCHUNKS);
    bspline_fused_kernel<<<grid, block, 0, stream>>>(x, cp, out);
}

// Round 6
// 402.912 us; speedup vs baseline: 1.0148x; 1.0148x over previous
//
#include <hip/hip_runtime.h>
#include <stdint.h>

// Problem constants (fixed by setup_inputs):
//   x: (16, 3, 1024, 1024) f32; control_points: (1, 2, 35, 35) f32
//   out = concat(transformed (16,3,1024,1024), deformation_field (2,1024,1024))
#define HW      1024
#define PLANE   (HW * HW)
#define NPLANES 48
#define CP      35
#define CPN     (CP * CP)          // 1225
#define PPT     8                  // planes per tile
#define NTILES  24576              // 6 z-chunks * 1024 rows * 4 col-chunks
#define BLOCKS  2048
#define KITER   (NTILES / BLOCKS)  // 12

typedef float f2v __attribute__((ext_vector_type(2)));

struct Slot {
    uint32_t vot, vob;             // byte offsets of row-Y0 / row-Y1 pairs
    float wax, wbx, uy, omuy;
    const float* xp;               // x + zc*PPT*PLANE
    float* op;                     // out + zc*PPT*PLANE + pix
};

// Decode tile -> sampling state. All memory traffic here is LDS (lgkmcnt),
// so it never perturbs the vmcnt pipeline ledger. df store (vmem) happens
// only for tiles < 4096 (the two prologue tiles), accounted in the ledger.
__device__ __forceinline__ void compute_addr(
    int tile, int tid, const float* __restrict__ scp,
    const float* __restrict__ x, float* __restrict__ out, Slot& s)
{
    const int zc  = tile >> 12;           // 0..5
    const int rem = tile & 4095;
    const int i   = rem >> 2;             // row
    const int j   = ((rem & 3) << 8) + tid;
    const int pix = i * HW + j;

    const float gx = (float)j * (2.0f / 1023.0f) - 1.0f;
    const float gy = (float)i * (2.0f / 1023.0f) - 1.0f;

    // deformation field: bilinear sample of control points (from LDS)
    const float cpxc = gx * 17.0f + 17.0f;
    const float cpyc = gy * 17.0f + 17.0f;
    float ix = (cpxc + 1.0f) * 0.5f * 34.0f;
    float iy = (cpyc + 1.0f) * 0.5f * 34.0f;
    ix = fminf(fmaxf(ix, 0.0f), 34.0f);
    iy = fminf(fmaxf(iy, 0.0f), 34.0f);
    const float ix0f = floorf(ix), iy0f = floorf(iy);
    const float wx = ix - ix0f,    wy = iy - iy0f;
    const int ix0 = (int)ix0f, iy0 = (int)iy0f;
    const int ix1 = min(ix0 + 1, 34), iy1 = min(iy0 + 1, 34);
    const int o00c = iy0 * CP + ix0, o01c = iy0 * CP + ix1;
    const int o10c = iy1 * CP + ix0, o11c = iy1 * CP + ix1;

    float df[2];
    #pragma unroll
    for (int c = 0; c < 2; ++c) {
        const float* cpc = scp + c * CPN;
        const float v00 = cpc[o00c], v01 = cpc[o01c];
        const float v10 = cpc[o10c], v11 = cpc[o11c];
        const float top = v00 * (1.0f - wx) + v01 * wx;
        const float bot = v10 * (1.0f - wx) + v11 * wx;
        df[c] = top * (1.0f - wy) + bot * wy;
    }

    // deformation_field written once per (i,j): exactly the zc==0 tiles,
    // i.e. tile < 4096 (only the two prologue tiles per block).
    if (tile < 4096) {
        out[(size_t)NPLANES * PLANE + pix] = df[0];
        out[(size_t)NPLANES * PLANE + PLANE + pix] = df[1];
    }

    // image sampling coords (df channel swap per reference)
    const float sxn = gx + df[1];
    const float syn = gy + df[0];
    float fx = (sxn + 1.0f) * 0.5f * 1023.0f;
    float fy = (syn + 1.0f) * 0.5f * 1023.0f;
    fx = fminf(fmaxf(fx, 0.0f), 1023.0f);
    fy = fminf(fmaxf(fy, 0.0f), 1023.0f);
    const float fx0f = floorf(fx), fy0f = floorf(fy);
    const float uy = fy - fy0f;
    const int X0 = (int)fx0f, Y0 = (int)fy0f;
    const int Y1 = min(Y0 + 1, 1023);

    // x-neighbor pair as one dwordx2; border fold (ux==0 at X0==1023):
    const int bshift = (X0 >= 1023) ? 1 : 0;
    s.vot  = (uint32_t)(Y0 * HW + X0 - bshift) * 4u;
    s.vob  = (uint32_t)(Y1 * HW + X0 - bshift) * 4u;
    s.wbx  = bshift ? 1.0f : (fx - fx0f);
    s.wax  = 1.0f - s.wbx;
    s.uy   = uy;
    s.omuy = 1.0f - uy;
    s.xp   = x   + (size_t)(zc * PPT) * PLANE;
    s.op   = out + (size_t)(zc * PPT) * PLANE + pix;
}

// Issue 16 dwordx2 gathers for one tile, NO wait (pipeline fill).
#define ISSUE_LOADS(P, S)                                                   \
    asm volatile(                                                           \
        "global_load_dwordx2 %[t0], %[ot], %[b0]\n\t"                       \
        "global_load_dwordx2 %[m0], %[ob], %[b0]\n\t"                       \
        "global_load_dwordx2 %[t1], %[ot], %[b1]\n\t"                       \
        "global_load_dwordx2 %[m1], %[ob], %[b1]\n\t"                       \
        "global_load_dwordx2 %[t2], %[ot], %[b2]\n\t"                       \
        "global_load_dwordx2 %[m2], %[ob], %[b2]\n\t"                       \
        "global_load_dwordx2 %[t3], %[ot], %[b3]\n\t"                       \
        "global_load_dwordx2 %[m3], %[ob], %[b3]\n\t"                       \
        "global_load_dwordx2 %[t4], %[ot], %[b4]\n\t"                       \
        "global_load_dwordx2 %[m4], %[ob], %[b4]\n\t"                       \
        "global_load_dwordx2 %[t5], %[ot], %[b5]\n\t"                       \
        "global_load_dwordx2 %[m5], %[ob], %[b5]\n\t"                       \
        "global_load_dwordx2 %[t6], %[ot], %[b6]\n\t"                       \
        "global_load_dwordx2 %[m6], %[ob], %[b6]\n\t"                       \
        "global_load_dwordx2 %[t7], %[ot], %[b7]\n\t"                       \
        "global_load_dwordx2 %[m7], %[ob], %[b7]"                           \
        : [t0]"=&v"(P##t0), [m0]"=&v"(P##m0), [t1]"=&v"(P##t1),             \
          [m1]"=&v"(P##m1), [t2]"=&v"(P##t2), [m2]"=&v"(P##m2),             \
          [t3]"=&v"(P##t3), [m3]"=&v"(P##m3), [t4]"=&v"(P##t4),             \
          [m4]"=&v"(P##m4), [t5]"=&v"(P##t5), [m5]"=&v"(P##m5),             \
          [t6]"=&v"(P##t6), [m6]"=&v"(P##m6), [t7]"=&v"(P##t7),             \
          [m7]"=&v"(P##m7)                                                  \
        : [ot]"v"((S).vot), [ob]"v"((S).vob),                               \
          [b0]"s"((S).xp),             [b1]"s"((S).xp + 1 * PLANE),         \
          [b2]"s"((S).xp + 2 * PLANE), [b3]"s"((S).xp + 3 * PLANE),         \
          [b4]"s"((S).xp + 4 * PLANE), [b5]"s"((S).xp + 5 * PLANE),         \
          [b6]"s"((S).xp + 6 * PLANE), [b7]"s"((S).xp + 7 * PLANE)          \
        : "memory")

// Counted wait: all but the newest N vmem ops are complete. Declares the
// buffer regs as inout so every consumer is data-dependent on the wait
// (rule #18), plus a sched_barrier belt-and-braces.
#define WAITV(P, N)                                                         \
    asm volatile("s_waitcnt vmcnt(" #N ")"                                  \
        : "+v"(P##t0), "+v"(P##m0), "+v"(P##t1), "+v"(P##m1),               \
          "+v"(P##t2), "+v"(P##m2), "+v"(P##t3), "+v"(P##m3),               \
          "+v"(P##t4), "+v"(P##m4), "+v"(P##t5), "+v"(P##m5),               \
          "+v"(P##t6), "+v"(P##m6), "+v"(P##t7), "+v"(P##m7)                \
        : : "memory");                                                      \
    __builtin_amdgcn_sched_barrier(0)

#define CS1(P, S, n) do {                                                   \
    const float _top = P##t##n.x * (S).wax + P##t##n.y * (S).wbx;           \
    const float _bot = P##m##n.x * (S).wax + P##m##n.y * (S).wbx;           \
    __builtin_nontemporal_store(_top * (S).omuy + _bot * (S).uy,            \
                                (S).op + (size_t)(n) * PLANE);              \
} while (0)

#define COMPUTE_STORE(P, S) do {                                            \
    CS1(P, S, 0); CS1(P, S, 1); CS1(P, S, 2); CS1(P, S, 3);                 \
    CS1(P, S, 4); CS1(P, S, 5); CS1(P, S, 6); CS1(P, S, 7);                 \
} while (0)

__global__ __launch_bounds__(256) void bspline_fused_kernel(
    const float* __restrict__ x,
    const float* __restrict__ cp,   // (2, 35, 35)
    float* __restrict__ out)
{
    // cp table -> LDS so per-tile df gathers are lgkmcnt ops (independent
    // of the vmcnt pipeline ledger).
    __shared__ float scp[2 * CPN];
    const int tid = threadIdx.x;
    for (int k = tid; k < 2 * CPN; k += 256) scp[k] = cp[k];
    __syncthreads();

    const int b = blockIdx.x;
    Slot s0, s1;
    f2v a_t0, a_m0, a_t1, a_m1, a_t2, a_m2, a_t3, a_m3,
        a_t4, a_m4, a_t5, a_m5, a_t6, a_m6, a_t7, a_m7;
    f2v b_t0, b_m0, b_t1, b_m1, b_t2, b_m2, b_t3, b_m3,
        b_t4, b_m4, b_t5, b_m5, b_t6, b_m6, b_t7, b_m7;

    // ---- pipeline ledger (per wave, FIFO; L=16 loads, S=8 stores) ----
    // prologue: dfS(t0) L(t0) dfS(t1) L(t1)
    // k=0  wait vmcnt(16): younger(L0) = L1(16)                      -> 16
    // k>=1 wait vmcnt(24): younger(Lk) = S(k-1)(8) + L(k+1)(16)      -> 24
    // k=11 wait vmcnt(8):  younger(L11) = S(10)(8)                   -> 8
    compute_addr(0 * BLOCKS + b, tid, scp, x, out, s0);
    ISSUE_LOADS(a_, s0);
    compute_addr(1 * BLOCKS + b, tid, scp, x, out, s1);
    ISSUE_LOADS(b_, s1);

    // k = 0 (buffer A)
    WAITV(a_, 16);
    COMPUTE_STORE(a_, s0);
    compute_addr(2 * BLOCKS + b, tid, scp, x, out, s0);
    ISSUE_LOADS(a_, s0);

    // k = 1..8 (pairs: odd->B, even->A); issues tiles 3..10
    for (int k = 1; k <= 7; k += 2) {
        WAITV(b_, 24);
        COMPUTE_STORE(b_, s1);
        compute_addr((k + 2) * BLOCKS + b, tid, scp, x, out, s1);
        ISSUE_LOADS(b_, s1);

        WAITV(a_, 24);
        COMPUTE_STORE(a_, s0);
        compute_addr((k + 3) * BLOCKS + b, tid, scp, x, out, s0);
        ISSUE_LOADS(a_, s0);
    }

    // k = 9 (B): last issue, tile 11
    WAITV(b_, 24);
    COMPUTE_STORE(b_, s1);
    compute_addr(11 * BLOCKS + b, tid, scp, x, out, s1);
    ISSUE_LOADS(b_, s1);

    // k = 10 (A): no further issue
    WAITV(a_, 24);
    COMPUTE_STORE(a_, s0);

    // k = 11 (B): drain
    WAITV(b_, 8);
    COMPUTE_STORE(b_, s1);
}

extern "C" void kernel_launch(void* const* d_in, const int* in_sizes, int n_in,
                              void* d_out, int out_size, void* d_ws, size_t ws_size,
                              hipStream_t stream) {
    const float* x  = (const float*)d_in[0];
    const float* cp = (const float*)d_in[1];
    float* out = (float*)d_out;

    dim3 block(256, 1, 1);
    dim3 grid(BLOCKS, 1, 1);
    bspline_fused_kernel<<<grid, block, 0, stream>>>(x, cp, out);
}